// Round 2
// baseline (1586.448 us; speedup 1.0000x reference)
//
#include <hip/hip_runtime.h>
#include <stdint.h>

#define T_DIM 512
#define B_DIM 256
#define OBS_DIM 128
#define H_DIM 256
#define TB (T_DIM * B_DIM)

typedef _Float16 f16;
typedef __attribute__((ext_vector_type(8))) _Float16 f16x8;
typedef __attribute__((ext_vector_type(4))) float f32x4;

union H2U { f16 h[2]; uint32_t u; };

__device__ __forceinline__ f32x4 fz4() { f32x4 v; v[0]=0.f; v[1]=0.f; v[2]=0.f; v[3]=0.f; return v; }
__device__ __forceinline__ float sigm(float x) {
  float e = __expf(-x);
  return __builtin_amdgcn_rcpf(1.f + e);
}
__device__ __forceinline__ float tanh_f(float x) {
  float e = __expf(-2.f * x);
  return (1.f - e) * __builtin_amdgcn_rcpf(1.f + e);
}

// ---------------------------------------------------------------------------
// K0: weights -> f16. encW 32768 | Wih 196608 | head 8192 (rows0-15 pol,16 val)
// ---------------------------------------------------------------------------
__global__ void k_prep(const float* __restrict__ encW, const float* __restrict__ Wih,
                       const float* __restrict__ polW, const float* __restrict__ valW,
                       f16* __restrict__ encW_h, f16* __restrict__ Wih_h,
                       f16* __restrict__ headW_h) {
  int e = blockIdx.x * 256 + threadIdx.x;
  if (e < 32768) { encW_h[e] = (f16)encW[e]; return; }
  e -= 32768;
  if (e < 196608) { Wih_h[e] = (f16)Wih[e]; return; }
  e -= 196608;
  if (e < 8192) {
    int r = e >> 8, c = e & 255;
    float v = (r < 16) ? polW[r * 256 + c] : (r == 16 ? valW[c] : 0.f);
    headW_h[e] = (f16)v;
  }
}

// ---------------------------------------------------------------------------
// K1: x = tanh(obs @ enc_W^T + enc_b) -> f16 into xgi. M-tile 128, grid 1024.
// ---------------------------------------------------------------------------
__global__ __launch_bounds__(512) void k_enc(const float* __restrict__ obs,
                                             const f16* __restrict__ encW_h,
                                             const float* __restrict__ enc_b,
                                             f16* __restrict__ xgi) {
  __shared__ f16 lA[128 * 64];  // 16KB [128 rows][64 k] swizzled
  __shared__ f16 lB[256 * 64];  // 32KB [256 n][64 k] swizzled
  const int tid = threadIdx.x, lane = tid & 63, w = tid >> 6;
  const int m0 = blockIdx.x * 128;
  f32x4 acc[16];
#pragma unroll
  for (int i = 0; i < 16; i++) acc[i] = fz4();

  for (int kc = 0; kc < 2; kc++) {
    const int k0c = kc * 64;
#pragma unroll
    for (int i = 0; i < 4; i++) {
      int c = tid + i * 512;
      int r = c >> 4, kk = (c & 15) * 4;
      float4 v = *(const float4*)(obs + (size_t)(m0 + r) * OBS_DIM + k0c + kk);
      H2U a, b;
      a.h[0] = (f16)v.x; a.h[1] = (f16)v.y; b.h[0] = (f16)v.z; b.h[1] = (f16)v.w;
      uint32_t off = ((uint32_t)(r * 128 + kk * 2)) ^ (((uint32_t)(r & 7)) << 4);
      uint2 p; p.x = a.u; p.y = b.u;
      *(uint2*)((char*)lA + off) = p;
    }
#pragma unroll
    for (int i = 0; i < 4; i++) {
      int c = tid + i * 512;
      int r = c >> 3, kk = (c & 7) * 8;
      f16x8 v = *(const f16x8*)(encW_h + (size_t)r * OBS_DIM + k0c + kk);
      uint32_t off = ((uint32_t)(r * 128 + kk * 2)) ^ (((uint32_t)(r & 7)) << 4);
      *(f16x8*)((char*)lB + off) = v;
    }
    __syncthreads();
#pragma unroll
    for (int ks = 0; ks < 2; ks++) {
      const int ar = w * 16 + (lane & 15);
      const int kofs = (ks * 32 + ((lane >> 4) << 3)) * 2;
      uint32_t aoff = ((uint32_t)(ar * 128 + kofs)) ^ (((uint32_t)(ar & 7)) << 4);
      f16x8 af = *(const f16x8*)((char*)lA + aoff);
#pragma unroll
      for (int i = 0; i < 16; i++) {
        const int br = i * 16 + (lane & 15);
        uint32_t boff = ((uint32_t)(br * 128 + kofs)) ^ (((uint32_t)(br & 7)) << 4);
        f16x8 bfr = *(const f16x8*)((char*)lB + boff);
        acc[i] = __builtin_amdgcn_mfma_f32_16x16x32_f16(af, bfr, acc[i], 0, 0, 0);
      }
    }
    __syncthreads();
  }
  const int mrow = m0 + w * 16 + ((lane >> 4) << 2);
#pragma unroll
  for (int i = 0; i < 16; i++) {
    const int col = i * 16 + (lane & 15);
    const float bb = enc_b[col];
#pragma unroll
    for (int r = 0; r < 4; r++) {
      float s = acc[i][r] + bb;
      xgi[(size_t)(mrow + r) * H_DIM + col] = (f16)tanh_f(s);
    }
  }
}

// ---------------------------------------------------------------------------
// K2: all 3 gates fused: gi = x @ W_ih^T + bias. M-tile 64, N=768, grid 2048.
// bias: b_ih + b_hh for r,z cols (<512); b_ih only for n.
// r,z -> gi_rz f16 [TB][512]; n -> xgi [TB][256] (overwrites x rows this
// block exclusively owns -- safe).
// ---------------------------------------------------------------------------
__global__ __launch_bounds__(512) void k_gi3(const f16* __restrict__ xgi_r,
                                             const f16* __restrict__ Wih_h,
                                             const float* __restrict__ b_ih,
                                             const float* __restrict__ b_hh,
                                             f16* __restrict__ gi_rz,
                                             f16* __restrict__ xgi_w) {
  __shared__ f16 lA[64 * 64];    // 8KB
  __shared__ f16 lB[768 * 64];   // 96KB
  const int tid = threadIdx.x, lane = tid & 63, w = tid >> 6;
  const int m0 = blockIdx.x * 64;
  const int mstrip = w >> 1, nh = w & 1;
  f32x4 acc[24];
#pragma unroll
  for (int i = 0; i < 24; i++) acc[i] = fz4();

  for (int kc = 0; kc < 4; kc++) {
    const int k0c = kc * 64;
    {
      int r = tid >> 3, kk = (tid & 7) * 8;
      f16x8 v = *(const f16x8*)(xgi_r + (size_t)(m0 + r) * H_DIM + k0c + kk);
      uint32_t off = ((uint32_t)(r * 128 + kk * 2)) ^ (((uint32_t)(r & 7)) << 4);
      *(f16x8*)((char*)lA + off) = v;
    }
#pragma unroll
    for (int i = 0; i < 12; i++) {
      int c = tid + i * 512;
      int r = c >> 3, kk = (c & 7) * 8;
      f16x8 v = *(const f16x8*)(Wih_h + (size_t)r * H_DIM + k0c + kk);
      uint32_t off = ((uint32_t)(r * 128 + kk * 2)) ^ (((uint32_t)(r & 7)) << 4);
      *(f16x8*)((char*)lB + off) = v;
    }
    __syncthreads();
#pragma unroll
    for (int ks = 0; ks < 2; ks++) {
      const int ar = mstrip * 16 + (lane & 15);
      const int kofs = (ks * 32 + ((lane >> 4) << 3)) * 2;
      uint32_t aoff = ((uint32_t)(ar * 128 + kofs)) ^ (((uint32_t)(ar & 7)) << 4);
      f16x8 af = *(const f16x8*)((char*)lA + aoff);
#pragma unroll
      for (int i = 0; i < 24; i++) {
        const int br = nh * 384 + i * 16 + (lane & 15);
        uint32_t boff = ((uint32_t)(br * 128 + kofs)) ^ (((uint32_t)(br & 7)) << 4);
        f16x8 bfr = *(const f16x8*)((char*)lB + boff);
        acc[i] = __builtin_amdgcn_mfma_f32_16x16x32_f16(af, bfr, acc[i], 0, 0, 0);
      }
    }
    __syncthreads();
  }
  const int mrow = m0 + mstrip * 16 + ((lane >> 4) << 2);
#pragma unroll
  for (int i = 0; i < 24; i++) {
    const int col = nh * 384 + i * 16 + (lane & 15);
    float bb = b_ih[col];
    if (col < 512) bb += b_hh[col];
#pragma unroll
    for (int r = 0; r < 4; r++) {
      float s = acc[i][r] + bb;
      size_t tb = (size_t)(mrow + r);
      if (col < 512) gi_rz[tb * 512 + col] = (f16)s;
      else           xgi_w[tb * 256 + (col - 512)] = (f16)s;
    }
  }
}

// ---------------------------------------------------------------------------
// K3: GRU scan. grid(16) x block 512 (8 waves), WG owns 16 batch rows.
// W_hh resident as 48 f16 MFMA B-frags (192 VGPR). gi double-buffered in LDS,
// prefetched one step ahead (register prefetch -> ds_write at phase-B end).
// outs (f16) overwrite gi_n element-wise (same thread, read-then-write).
// ---------------------------------------------------------------------------
__global__ __launch_bounds__(512) void k_scan(const float* __restrict__ Whh,
                                              const float* __restrict__ b_hh,
                                              const float* __restrict__ done,
                                              const f16* __restrict__ gi_rz,
                                              f16* __restrict__ xgi) {
  __shared__ f16 h_l[16 * 256];        // 8KB, swizzled, row=batch
  __shared__ float done_l[16 + 8192];  // 32.06KB, done_l[16 + t*16 + j]; first 16 = 0
  __shared__ f16 rz_l[2][16][528];     // 33KB, pad 16 -> stride 1056B (=8 mod 32 dw)
  __shared__ f16 gn_l[2][16][272];     // 17KB, pad 16 -> stride 544B  (=8 mod 32 dw)
  const int tid = threadIdx.x, lane = tid & 63, w = tid >> 6;
  const int b0 = blockIdx.x * 16;

#pragma unroll
  for (int i = 0; i < 16; i++) {
    int e = tid + i * 512;
    done_l[16 + e] = done[(size_t)(e >> 4) * B_DIM + b0 + (e & 15)];
  }
  if (tid < 16) done_l[tid] = 0.f;
#pragma unroll
  for (int i = 0; i < 8; i++) h_l[tid + i * 512] = (f16)0.f;

  // resident W_hh fragments
  f16x8 wf[3][2][8];
#pragma unroll
  for (int g = 0; g < 3; g++) {
#pragma unroll
    for (int hh = 0; hh < 2; hh++) {
      const int row = g * 256 + w * 32 + hh * 16 + (lane & 15);
      const float* wrow = Whh + (size_t)row * H_DIM;
#pragma unroll
      for (int ks = 0; ks < 8; ks++) {
        const int k0 = ks * 32 + ((lane >> 4) << 3);
        float4 a = *(const float4*)(wrow + k0);
        float4 b = *(const float4*)(wrow + k0 + 4);
        f16x8 f;
        f[0] = (f16)a.x; f[1] = (f16)a.y; f[2] = (f16)a.z; f[3] = (f16)a.w;
        f[4] = (f16)b.x; f[5] = (f16)b.y; f[6] = (f16)b.z; f[7] = (f16)b.w;
        wf[g][hh][ks] = f;
      }
    }
  }
  float bhhn[2];
#pragma unroll
  for (int hh = 0; hh < 2; hh++)
    bhhn[hh] = b_hh[512 + w * 32 + hh * 16 + (lane & 15)];

  // prologue: stage gi(t=0) into buf0
  {
    const uint4* g_rz = (const uint4*)(gi_rz + (size_t)b0 * 512);
    const uint4* g_n  = (const uint4*)(xgi + (size_t)b0 * 256);
    uint4 p0 = g_rz[tid], p1 = g_rz[tid + 512], p2 = g_n[tid];
    *(uint4*)&rz_l[0][tid >> 6][(tid & 63) * 8] = p0;
    *(uint4*)&rz_l[0][(tid >> 6) + 8][(tid & 63) * 8] = p1;
    *(uint4*)&gn_l[0][tid >> 5][(tid & 31) * 8] = p2;
  }
  __syncthreads();

  for (int t = 0; t < T_DIM; t++) {
    // prefetch gi for t+1 (registers; consumed at end of phase B)
    const int ts = (t + 1 < T_DIM) ? (t + 1) : (T_DIM - 1);
    const uint4* g_rz = (const uint4*)(gi_rz + ((size_t)ts * B_DIM + b0) * 512);
    const uint4* g_n  = (const uint4*)(xgi + ((size_t)ts * B_DIM + b0) * 256);
    uint4 p0 = g_rz[tid];
    uint4 p1 = g_rz[tid + 512];
    uint4 p2 = g_n[tid];

    // phase A: gh = mask(h) @ W_hh^T
    const float pda = done_l[t * 16 + (lane & 15)];
    const bool zA = (pda != 0.f);
    f32x4 acc[3][2];
#pragma unroll
    for (int g = 0; g < 3; g++)
#pragma unroll
      for (int hh = 0; hh < 2; hh++) acc[g][hh] = fz4();
#pragma unroll
    for (int ks = 0; ks < 8; ks++) {
      const int ar = lane & 15;
      uint32_t aoff = ((uint32_t)(ar * 512 + (ks * 32 + ((lane >> 4) << 3)) * 2)) ^
                      (((uint32_t)(ar & 7)) << 4);
      f16x8 af = *(const f16x8*)((char*)h_l + aoff);
      if (zA) { f16x8 zv = {}; af = zv; }
#pragma unroll
      for (int g = 0; g < 3; g++)
#pragma unroll
        for (int hh = 0; hh < 2; hh++)
          acc[g][hh] = __builtin_amdgcn_mfma_f32_16x16x32_f16(af, wf[g][hh][ks], acc[g][hh], 0, 0, 0);
    }
    __syncthreads();  // h reads done; gi buf[t&1] complete

    // phase B: gates + update
    const int cb = t & 1, nb = cb ^ 1;
#pragma unroll
    for (int hh = 0; hh < 2; hh++) {
      const int col = w * 32 + hh * 16 + (lane & 15);
#pragma unroll
      for (int r = 0; r < 4; r++) {
        const int bi = ((lane >> 4) << 2) + r;
        const float pd = done_l[t * 16 + bi];
        uint32_t hoff = ((uint32_t)(bi * 512 + col * 2)) ^ (((uint32_t)(bi & 7)) << 4);
        float hp = (float)*(const f16*)((char*)h_l + hoff);
        hp = (pd != 0.f) ? 0.f : hp;
        const float gr = (float)rz_l[cb][bi][col];
        const float gz = (float)rz_l[cb][bi][256 + col];
        const float gn = (float)gn_l[cb][bi][col];
        const float rr = sigm(gr + acc[0][hh][r]);
        const float zz = sigm(gz + acc[1][hh][r]);
        const float nn = tanh_f(gn + rr * (acc[2][hh][r] + bhhn[hh]));
        const float hn = nn + zz * (hp - nn);
        *(f16*)((char*)h_l + hoff) = (f16)hn;
      }
    }
    // write prefetched gi(t+1) into buf nb
    *(uint4*)&rz_l[nb][tid >> 6][(tid & 63) * 8] = p0;
    *(uint4*)&rz_l[nb][(tid >> 6) + 8][(tid & 63) * 8] = p1;
    *(uint4*)&gn_l[nb][tid >> 5][(tid & 31) * 8] = p2;
    __syncthreads();  // h + gi buf visible

    // phase C: h -> outs (wide 16B stores), overwrites gi_n rows of step t
    {
      const int row = tid >> 5, o = tid & 31;
      uint32_t loff = ((uint32_t)(row * 512 + o * 16)) ^ (((uint32_t)(row & 7)) << 4);
      f16x8 hv = *(const f16x8*)((char*)h_l + loff);
      *(f16x8*)(xgi + ((size_t)t * B_DIM + b0 + row) * 256 + o * 8) = hv;
    }
  }
}

// ---------------------------------------------------------------------------
// K4: heads. M-tile 64, N=32 (16 pol + 1 val + pad), grid 2048, block 256.
// ---------------------------------------------------------------------------
__global__ __launch_bounds__(256) void k_heads(const f16* __restrict__ outs,
                                               const f16* __restrict__ headW_h,
                                               const float* __restrict__ pol_b,
                                               const float* __restrict__ val_b,
                                               float* __restrict__ out) {
  __shared__ f16 lA[64 * 256];  // 32KB swizzled
  __shared__ f16 lB[32 * 256];  // 16KB
  const int tid = threadIdx.x, lane = tid & 63, w = tid >> 6;
  const int m0 = blockIdx.x * 64;
#pragma unroll
  for (int i = 0; i < 8; i++) {
    int c = tid + i * 256;
    int r = c >> 5, o = (c & 31) * 8;
    f16x8 v = *(const f16x8*)(outs + (size_t)(m0 + r) * H_DIM + o);
    uint32_t off = ((uint32_t)(r * 512 + o * 2)) ^ (((uint32_t)(r & 7)) << 4);
    *(f16x8*)((char*)lA + off) = v;
  }
#pragma unroll
  for (int i = 0; i < 4; i++) {
    int c = tid + i * 256;
    int r = c >> 5, o = (c & 31) * 8;
    f16x8 v = *(const f16x8*)(headW_h + (size_t)r * H_DIM + o);
    uint32_t off = ((uint32_t)(r * 512 + o * 2)) ^ (((uint32_t)(r & 7)) << 4);
    *(f16x8*)((char*)lB + off) = v;
  }
  __syncthreads();
  f32x4 acc[2];
  acc[0] = fz4(); acc[1] = fz4();
#pragma unroll
  for (int ks = 0; ks < 8; ks++) {
    const int ar = w * 16 + (lane & 15);
    const int kofs = (ks * 32 + ((lane >> 4) << 3)) * 2;
    uint32_t aoff = ((uint32_t)(ar * 512 + kofs)) ^ (((uint32_t)(ar & 7)) << 4);
    f16x8 af = *(const f16x8*)((char*)lA + aoff);
#pragma unroll
    for (int nt = 0; nt < 2; nt++) {
      const int br = nt * 16 + (lane & 15);
      uint32_t boff = ((uint32_t)(br * 512 + kofs)) ^ (((uint32_t)(br & 7)) << 4);
      f16x8 bfr = *(const f16x8*)((char*)lB + boff);
      acc[nt] = __builtin_amdgcn_mfma_f32_16x16x32_f16(af, bfr, acc[nt], 0, 0, 0);
    }
  }
  const int n = lane & 15;
  const float pb = pol_b[n];
  const float vb = val_b[0];
#pragma unroll
  for (int r = 0; r < 4; r++) {
    const int mrow = m0 + w * 16 + ((lane >> 4) << 2) + r;
    out[(size_t)mrow * 16 + n] = acc[0][r] + pb;
    if (n == 0) out[(size_t)TB * 16 + mrow] = acc[1][r] + vb;
  }
}

// ---------------------------------------------------------------------------
// Workspace layout (192.5 MiB total):
//   [0,128Mi)        gi_rz f16 [TB][512]
//   [128Mi,192Mi)    xgi  f16 [TB][256]  (x -> gi_n -> outs, provably race-free)
//   [192Mi,+475KB)   encW_h | Wih_h | headW_h
// ---------------------------------------------------------------------------
extern "C" void kernel_launch(void* const* d_in, const int* in_sizes, int n_in,
                              void* d_out, int out_size, void* d_ws, size_t ws_size,
                              hipStream_t stream) {
  (void)in_sizes; (void)n_in; (void)out_size; (void)ws_size;
  const float* obs   = (const float*)d_in[0];
  const float* done  = (const float*)d_in[1];
  const float* encW  = (const float*)d_in[2];
  const float* enc_b = (const float*)d_in[3];
  const float* Wih   = (const float*)d_in[4];
  const float* Whh   = (const float*)d_in[5];
  const float* b_ih  = (const float*)d_in[6];
  const float* b_hh  = (const float*)d_in[7];
  const float* polW  = (const float*)d_in[8];
  const float* pol_b = (const float*)d_in[9];
  const float* valW  = (const float*)d_in[10];
  const float* val_b = (const float*)d_in[11];

  char* ws = (char*)d_ws;
  f16* gi_rz   = (f16*)ws;
  f16* xgi     = (f16*)(ws + (size_t)134217728);
  f16* encW_h  = (f16*)(ws + (size_t)201326592);
  f16* Wih_h   = encW_h + 32768;
  f16* headW_h = Wih_h + 196608;
  float* outp  = (float*)d_out;

  k_prep<<<dim3(928), dim3(256), 0, stream>>>(encW, Wih, polW, valW, encW_h, Wih_h, headW_h);
  k_enc<<<dim3(1024), dim3(512), 0, stream>>>(obs, encW_h, enc_b, xgi);
  k_gi3<<<dim3(2048), dim3(512), 0, stream>>>(xgi, Wih_h, b_ih, b_hh, gi_rz, xgi);
  k_scan<<<dim3(16), dim3(512), 0, stream>>>(Whh, b_hh, done, gi_rz, xgi);
  k_heads<<<dim3(2048), dim3(256), 0, stream>>>(xgi, headW_h, pol_b, val_b, outp);
}

// Round 3
// 836.890 us; speedup vs baseline: 1.8956x; 1.8956x over previous
//
#include <hip/hip_runtime.h>
#include <stdint.h>

#define T_DIM 512
#define B_DIM 256
#define OBS_DIM 128
#define H_DIM 256
#define TB (T_DIM * B_DIM)

typedef _Float16 f16;
typedef __attribute__((ext_vector_type(8))) _Float16 f16x8;
typedef __attribute__((ext_vector_type(4))) float f32x4;

union H2U { f16 h[2]; uint32_t u; };

__device__ __forceinline__ f32x4 fz4() { f32x4 v; v[0]=0.f; v[1]=0.f; v[2]=0.f; v[3]=0.f; return v; }
__device__ __forceinline__ float sigm(float x) {
  float e = __expf(-x);
  return __builtin_amdgcn_rcpf(1.f + e);
}
__device__ __forceinline__ float tanh_f(float x) {
  float e = __expf(-2.f * x);
  return (1.f - e) * __builtin_amdgcn_rcpf(1.f + e);
}

// ---------------------------------------------------------------------------
// K0: weights -> f16. encW 32768 | Wih 196608 | head 8192 (rows0-15 pol,16 val)
// ---------------------------------------------------------------------------
__global__ void k_prep(const float* __restrict__ encW, const float* __restrict__ Wih,
                       const float* __restrict__ polW, const float* __restrict__ valW,
                       f16* __restrict__ encW_h, f16* __restrict__ Wih_h,
                       f16* __restrict__ headW_h) {
  int e = blockIdx.x * 256 + threadIdx.x;
  if (e < 32768) { encW_h[e] = (f16)encW[e]; return; }
  e -= 32768;
  if (e < 196608) { Wih_h[e] = (f16)Wih[e]; return; }
  e -= 196608;
  if (e < 8192) {
    int r = e >> 8, c = e & 255;
    float v = (r < 16) ? polW[r * 256 + c] : (r == 16 ? valW[c] : 0.f);
    headW_h[e] = (f16)v;
  }
}

// ---------------------------------------------------------------------------
// K1: x = tanh(obs @ enc_W^T + enc_b) -> f16 into xgi. M-tile 128, grid 1024.
// ---------------------------------------------------------------------------
__global__ __launch_bounds__(512) void k_enc(const float* __restrict__ obs,
                                             const f16* __restrict__ encW_h,
                                             const float* __restrict__ enc_b,
                                             f16* __restrict__ xgi) {
  __shared__ f16 lA[128 * 64];  // 16KB [128 rows][64 k] swizzled
  __shared__ f16 lB[256 * 64];  // 32KB [256 n][64 k] swizzled
  const int tid = threadIdx.x, lane = tid & 63, w = tid >> 6;
  const int m0 = blockIdx.x * 128;
  f32x4 acc[16];
#pragma unroll
  for (int i = 0; i < 16; i++) acc[i] = fz4();

  for (int kc = 0; kc < 2; kc++) {
    const int k0c = kc * 64;
#pragma unroll
    for (int i = 0; i < 4; i++) {
      int c = tid + i * 512;
      int r = c >> 4, kk = (c & 15) * 4;
      float4 v = *(const float4*)(obs + (size_t)(m0 + r) * OBS_DIM + k0c + kk);
      H2U a, b;
      a.h[0] = (f16)v.x; a.h[1] = (f16)v.y; b.h[0] = (f16)v.z; b.h[1] = (f16)v.w;
      uint32_t off = ((uint32_t)(r * 128 + kk * 2)) ^ (((uint32_t)(r & 7)) << 4);
      uint2 p; p.x = a.u; p.y = b.u;
      *(uint2*)((char*)lA + off) = p;
    }
#pragma unroll
    for (int i = 0; i < 4; i++) {
      int c = tid + i * 512;
      int r = c >> 3, kk = (c & 7) * 8;
      f16x8 v = *(const f16x8*)(encW_h + (size_t)r * OBS_DIM + k0c + kk);
      uint32_t off = ((uint32_t)(r * 128 + kk * 2)) ^ (((uint32_t)(r & 7)) << 4);
      *(f16x8*)((char*)lB + off) = v;
    }
    __syncthreads();
#pragma unroll
    for (int ks = 0; ks < 2; ks++) {
      const int ar = w * 16 + (lane & 15);
      const int kofs = (ks * 32 + ((lane >> 4) << 3)) * 2;
      uint32_t aoff = ((uint32_t)(ar * 128 + kofs)) ^ (((uint32_t)(ar & 7)) << 4);
      f16x8 af = *(const f16x8*)((char*)lA + aoff);
#pragma unroll
      for (int i = 0; i < 16; i++) {
        const int br = i * 16 + (lane & 15);
        uint32_t boff = ((uint32_t)(br * 128 + kofs)) ^ (((uint32_t)(br & 7)) << 4);
        f16x8 bfr = *(const f16x8*)((char*)lB + boff);
        acc[i] = __builtin_amdgcn_mfma_f32_16x16x32_f16(af, bfr, acc[i], 0, 0, 0);
      }
    }
    __syncthreads();
  }
  const int mrow = m0 + w * 16 + ((lane >> 4) << 2);
#pragma unroll
  for (int i = 0; i < 16; i++) {
    const int col = i * 16 + (lane & 15);
    const float bb = enc_b[col];
#pragma unroll
    for (int r = 0; r < 4; r++) {
      float s = acc[i][r] + bb;
      xgi[(size_t)(mrow + r) * H_DIM + col] = (f16)tanh_f(s);
    }
  }
}

// ---------------------------------------------------------------------------
// K2: all 3 gates fused: gi = x @ W_ih^T + bias. M-tile 64, N=768, grid 2048.
// bias: b_ih + b_hh for r,z cols (<512); b_ih only for n.
// r,z -> gi_rz f16 [TB][256][2] INTERLEAVED (r,z adjacent) for the scan's
// single-u32 per-lane load; n -> xgi [TB][256] (overwrites x rows this
// block exclusively owns -- safe).
// ---------------------------------------------------------------------------
__global__ __launch_bounds__(512) void k_gi3(const f16* __restrict__ xgi_r,
                                             const f16* __restrict__ Wih_h,
                                             const float* __restrict__ b_ih,
                                             const float* __restrict__ b_hh,
                                             f16* __restrict__ gi_rz,
                                             f16* __restrict__ xgi_w) {
  __shared__ f16 lA[64 * 64];    // 8KB
  __shared__ f16 lB[768 * 64];   // 96KB
  const int tid = threadIdx.x, lane = tid & 63, w = tid >> 6;
  const int m0 = blockIdx.x * 64;
  const int mstrip = w >> 1, nh = w & 1;
  f32x4 acc[24];
#pragma unroll
  for (int i = 0; i < 24; i++) acc[i] = fz4();

  for (int kc = 0; kc < 4; kc++) {
    const int k0c = kc * 64;
    {
      int r = tid >> 3, kk = (tid & 7) * 8;
      f16x8 v = *(const f16x8*)(xgi_r + (size_t)(m0 + r) * H_DIM + k0c + kk);
      uint32_t off = ((uint32_t)(r * 128 + kk * 2)) ^ (((uint32_t)(r & 7)) << 4);
      *(f16x8*)((char*)lA + off) = v;
    }
#pragma unroll
    for (int i = 0; i < 12; i++) {
      int c = tid + i * 512;
      int r = c >> 3, kk = (c & 7) * 8;
      f16x8 v = *(const f16x8*)(Wih_h + (size_t)r * H_DIM + k0c + kk);
      uint32_t off = ((uint32_t)(r * 128 + kk * 2)) ^ (((uint32_t)(r & 7)) << 4);
      *(f16x8*)((char*)lB + off) = v;
    }
    __syncthreads();
#pragma unroll
    for (int ks = 0; ks < 2; ks++) {
      const int ar = mstrip * 16 + (lane & 15);
      const int kofs = (ks * 32 + ((lane >> 4) << 3)) * 2;
      uint32_t aoff = ((uint32_t)(ar * 128 + kofs)) ^ (((uint32_t)(ar & 7)) << 4);
      f16x8 af = *(const f16x8*)((char*)lA + aoff);
#pragma unroll
      for (int i = 0; i < 24; i++) {
        const int br = nh * 384 + i * 16 + (lane & 15);
        uint32_t boff = ((uint32_t)(br * 128 + kofs)) ^ (((uint32_t)(br & 7)) << 4);
        f16x8 bfr = *(const f16x8*)((char*)lB + boff);
        acc[i] = __builtin_amdgcn_mfma_f32_16x16x32_f16(af, bfr, acc[i], 0, 0, 0);
      }
    }
    __syncthreads();
  }
  const int mrow = m0 + mstrip * 16 + ((lane >> 4) << 2);
#pragma unroll
  for (int i = 0; i < 24; i++) {
    const int col = nh * 384 + i * 16 + (lane & 15);
    float bb = b_ih[col];
    if (col < 512) bb += b_hh[col];
#pragma unroll
    for (int r = 0; r < 4; r++) {
      float s = acc[i][r] + bb;
      size_t tb = (size_t)(mrow + r);
      if (col < 512) gi_rz[tb * 512 + (size_t)((col & 255) * 2 + (col >> 8))] = (f16)s;
      else           xgi_w[tb * 256 + (col - 512)] = (f16)s;
    }
  }
}

// ---------------------------------------------------------------------------
// K3: GRU scan v3. grid(128) x block 512 (8 waves), WG owns 2 batch rows.
// W_hh resident as 48 f16 MFMA B-frags. Per step: MFMA (M=16, rows 2-15 zero)
// -> wave-local gh redistribution through LDS (no barrier, in-wave LDS order
// + threadfence) -> exactly ONE h-output per lane (6 trans) -> masked h write
// to double-buffered h_l -> single __syncthreads per step.
// gi loaded per-lane straight from global (2 loads, issued at step top,
// hidden under MFMA). outs written per-lane (overwrites gi_n, same thread).
// ---------------------------------------------------------------------------
__global__ __launch_bounds__(512) void k_scan(const float* __restrict__ Whh,
                                              const float* __restrict__ b_hh,
                                              const float* __restrict__ done,
                                              const uint32_t* __restrict__ gi_rz,
                                              f16* xgi) {
  __shared__ f16 h_l[2][16][264];      // 16.5KB, double-buffered, rows 2-15 stay 0
  __shared__ float gh_l[8][6][16][2];  // 6KB [wave][g*2+hh][col&15][row]
  __shared__ float done_l[T_DIM][2];   // 4KB
  const int tid = threadIdx.x, lane = tid & 63, w = tid >> 6;
  const int b0 = blockIdx.x * 2;

  for (int i = tid; i < 2 * 16 * 264; i += 512) ((f16*)h_l)[i] = (f16)0.f;
  {
    float2 dv = *(const float2*)(done + (size_t)tid * B_DIM + b0);
    done_l[tid][0] = dv.x; done_l[tid][1] = dv.y;
  }

  // resident W_hh fragments (B-operand: rows of W_hh = gate cols, k = H)
  f16x8 wf[6][8];
#pragma unroll
  for (int g = 0; g < 3; g++) {
#pragma unroll
    for (int hh = 0; hh < 2; hh++) {
      const int rowW = g * 256 + w * 32 + hh * 16 + (lane & 15);
      const float* wrow = Whh + (size_t)rowW * H_DIM;
#pragma unroll
      for (int ks = 0; ks < 8; ks++) {
        const int k0 = ks * 32 + ((lane >> 4) << 3);
        float4 a = *(const float4*)(wrow + k0);
        float4 b = *(const float4*)(wrow + k0 + 4);
        f16x8 f;
        f[0] = (f16)a.x; f[1] = (f16)a.y; f[2] = (f16)a.z; f[3] = (f16)a.w;
        f[4] = (f16)b.x; f[5] = (f16)b.y; f[6] = (f16)b.z; f[7] = (f16)b.w;
        wf[g * 2 + hh][ks] = f;
      }
    }
  }
  const int row = lane >> 5, c = lane & 31, col = (w << 5) + c;
  const float bhhn = b_hh[512 + col];
  __syncthreads();

  for (int t = 0; t < T_DIM; t++) {
    const size_t tb = (size_t)t * B_DIM + b0 + row;
    // per-lane gi loads: consumed after MFMA (latency hidden)
    const uint32_t rzv = gi_rz[tb * 256 + col];
    const f16 gnv = xgi[tb * 256 + col];

    const int cur = t & 1, nxt = cur ^ 1;
    f32x4 acc[6];
#pragma unroll
    for (int i = 0; i < 6; i++) acc[i] = fz4();
#pragma unroll
    for (int ks = 0; ks < 8; ks++) {
      const f16x8 af = *(const f16x8*)&h_l[cur][lane & 15][ks * 32 + ((lane >> 4) << 3)];
#pragma unroll
      for (int i = 0; i < 6; i++)
        acc[i] = __builtin_amdgcn_mfma_f32_16x16x32_f16(af, wf[i][ks], acc[i], 0, 0, 0);
    }
    // wave-local gh redistribution (lanes 0-15 hold rows 0-3 of C-frag)
    if (lane < 16) {
#pragma unroll
      for (int i = 0; i < 6; i++) {
        float2 v; v.x = acc[i][0]; v.y = acc[i][1];
        *(float2*)&gh_l[w][i][lane][0] = v;
      }
    }
    __threadfence_block();  // in-wave LDS order + compiler fence; no barrier needed
    const int hh = c >> 4, cl = c & 15;
    const float ghr = gh_l[w][0 + hh][cl][row];
    const float ghz = gh_l[w][2 + hh][cl][row];
    const float ghn = gh_l[w][4 + hh][cl][row];
    H2U u; u.u = rzv;
    const float gr = (float)u.h[0], gz = (float)u.h[1], gn = (float)gnv;
    const float hp = (float)h_l[cur][row][col];
    const float rr = sigm(gr + ghr);
    const float zz = sigm(gz + ghz);
    const float nn = tanh_f(gn + rr * (ghn + bhhn));
    const float ho = nn + zz * (hp - nn);
    xgi[tb * 256 + col] = (f16)ho;                       // outs (same addr as gnv)
    const float dn = done_l[t][row];                     // masks h into step t+1
    h_l[nxt][row][col] = (f16)((dn != 0.f) ? 0.f : ho);
    __syncthreads();
  }
}

// ---------------------------------------------------------------------------
// K4: heads. M-tile 64, N=32 (16 pol + 1 val + pad), grid 2048, block 256.
// ---------------------------------------------------------------------------
__global__ __launch_bounds__(256) void k_heads(const f16* __restrict__ outs,
                                               const f16* __restrict__ headW_h,
                                               const float* __restrict__ pol_b,
                                               const float* __restrict__ val_b,
                                               float* __restrict__ out) {
  __shared__ f16 lA[64 * 256];  // 32KB swizzled
  __shared__ f16 lB[32 * 256];  // 16KB
  const int tid = threadIdx.x, lane = tid & 63, w = tid >> 6;
  const int m0 = blockIdx.x * 64;
#pragma unroll
  for (int i = 0; i < 8; i++) {
    int c = tid + i * 256;
    int r = c >> 5, o = (c & 31) * 8;
    f16x8 v = *(const f16x8*)(outs + (size_t)(m0 + r) * H_DIM + o);
    uint32_t off = ((uint32_t)(r * 512 + o * 2)) ^ (((uint32_t)(r & 7)) << 4);
    *(f16x8*)((char*)lA + off) = v;
  }
#pragma unroll
  for (int i = 0; i < 4; i++) {
    int c = tid + i * 256;
    int r = c >> 5, o = (c & 31) * 8;
    f16x8 v = *(const f16x8*)(headW_h + (size_t)r * H_DIM + o);
    uint32_t off = ((uint32_t)(r * 512 + o * 2)) ^ (((uint32_t)(r & 7)) << 4);
    *(f16x8*)((char*)lB + off) = v;
  }
  __syncthreads();
  f32x4 acc[2];
  acc[0] = fz4(); acc[1] = fz4();
#pragma unroll
  for (int ks = 0; ks < 8; ks++) {
    const int ar = w * 16 + (lane & 15);
    const int kofs = (ks * 32 + ((lane >> 4) << 3)) * 2;
    uint32_t aoff = ((uint32_t)(ar * 512 + kofs)) ^ (((uint32_t)(ar & 7)) << 4);
    f16x8 af = *(const f16x8*)((char*)lA + aoff);
#pragma unroll
    for (int nt = 0; nt < 2; nt++) {
      const int br = nt * 16 + (lane & 15);
      uint32_t boff = ((uint32_t)(br * 512 + kofs)) ^ (((uint32_t)(br & 7)) << 4);
      f16x8 bfr = *(const f16x8*)((char*)lB + boff);
      acc[nt] = __builtin_amdgcn_mfma_f32_16x16x32_f16(af, bfr, acc[nt], 0, 0, 0);
    }
  }
  const int n = lane & 15;
  const float pb = pol_b[n];
  const float vb = val_b[0];
#pragma unroll
  for (int r = 0; r < 4; r++) {
    const int mrow = m0 + w * 16 + ((lane >> 4) << 2) + r;
    out[(size_t)mrow * 16 + n] = acc[0][r] + pb;
    if (n == 0) out[(size_t)TB * 16 + mrow] = acc[1][r] + vb;
  }
}

// ---------------------------------------------------------------------------
// Workspace layout (192.5 MiB total, same as the passing round-2 layout):
//   [0,128Mi)        gi_rz f16 [TB][256][2]  (r,z interleaved)
//   [128Mi,192Mi)    xgi  f16 [TB][256]  (x -> gi_n -> outs, race-free)
//   [192Mi,+475KB)   encW_h | Wih_h | headW_h
// ---------------------------------------------------------------------------
extern "C" void kernel_launch(void* const* d_in, const int* in_sizes, int n_in,
                              void* d_out, int out_size, void* d_ws, size_t ws_size,
                              hipStream_t stream) {
  (void)in_sizes; (void)n_in; (void)out_size; (void)ws_size;
  const float* obs   = (const float*)d_in[0];
  const float* done  = (const float*)d_in[1];
  const float* encW  = (const float*)d_in[2];
  const float* enc_b = (const float*)d_in[3];
  const float* Wih   = (const float*)d_in[4];
  const float* Whh   = (const float*)d_in[5];
  const float* b_ih  = (const float*)d_in[6];
  const float* b_hh  = (const float*)d_in[7];
  const float* polW  = (const float*)d_in[8];
  const float* pol_b = (const float*)d_in[9];
  const float* valW  = (const float*)d_in[10];
  const float* val_b = (const float*)d_in[11];

  char* ws = (char*)d_ws;
  f16* gi_rz   = (f16*)ws;
  f16* xgi     = (f16*)(ws + (size_t)134217728);
  f16* encW_h  = (f16*)(ws + (size_t)201326592);
  f16* Wih_h   = encW_h + 32768;
  f16* headW_h = Wih_h + 196608;
  float* outp  = (float*)d_out;

  k_prep<<<dim3(928), dim3(256), 0, stream>>>(encW, Wih, polW, valW, encW_h, Wih_h, headW_h);
  k_enc<<<dim3(1024), dim3(512), 0, stream>>>(obs, encW_h, enc_b, xgi);
  k_gi3<<<dim3(2048), dim3(512), 0, stream>>>(xgi, Wih_h, b_ih, b_hh, gi_rz, xgi);
  k_scan<<<dim3(128), dim3(512), 0, stream>>>(Whh, b_hh, done, (const uint32_t*)gi_rz, xgi);
  k_heads<<<dim3(2048), dim3(256), 0, stream>>>(xgi, headW_h, pol_b, val_b, outp);
}